// Round 1
// baseline (1291.452 us; speedup 1.0000x reference)
//
#include <hip/hip_runtime.h>
#include <math.h>

#define G_NUM 1024
#define H 128
#define NNODES 100000
#define NEDGES 500000
#define EPS_LN 1e-5f

typedef __attribute__((ext_vector_type(8))) short short8;
typedef __attribute__((ext_vector_type(4))) float f32x4;

__device__ __forceinline__ float gelu_exact(float x) {
    return 0.5f * x * (1.0f + erff(x * 0.70710678118654752440f));
}
__device__ __forceinline__ unsigned short f2bf(float x) {
    unsigned u = __float_as_uint(x);
    return (unsigned short)((u + 0x7FFFu + ((u >> 16) & 1u)) >> 16);
}

// ---- K0: probe selected_mask storage dtype ----------------------------------
__global__ void k_probe_mask(const unsigned* __restrict__ mw, int* __restrict__ flag) {
    unsigned v = mw[threadIdx.x];
    if (v == 0x3F800000u) atomicOr(flag, 2);
    else if (v > 1u) atomicOr(flag, 1);
}

// ---- K_prep: W1' = diag(blng)*bw1, bf16, B-fragment order -------------------
// dst: ((s*8 + t8)*64 + lane)*8 + j ; s=k>>5, quad=(k&31)>>3, j=k&7,
// lane=quad*16+(n&15), t8=n>>4
__global__ void k_prep(const float* __restrict__ bw1, const float* __restrict__ blng,
                       unsigned short* __restrict__ bwbf) {
    int e = blockIdx.x * 256 + threadIdx.x;
    if (e >= 384 * 128) return;
    int k = e >> 7, n = e & 127;
    int s = k >> 5, krel = k & 31;
    int quad = krel >> 3, j = krel & 7;
    int lane = quad * 16 + (n & 15);
    int t8 = n >> 4;
    bwbf[((s * 8 + t8) * 64 + lane) * 8 + j] = f2bf(bw1[e] * blng[k]);
}

// ---- K_prep2: colsum[n] = sum_k blng[k]*bw1[k][n]; bb1p[n] = bb1[n]+sum_k blnb[k]*bw1[k][n]
__global__ __launch_bounds__(128) void k_prep2(const float* __restrict__ bw1,
                                               const float* __restrict__ blng,
                                               const float* __restrict__ blnb,
                                               const float* __restrict__ bb1,
                                               float* __restrict__ colsum,
                                               float* __restrict__ bb1p) {
    int n = threadIdx.x;
    float cs = 0.f, bs = 0.f;
    for (int k = 0; k < 384; ++k) {
        float w = bw1[k * H + n];
        cs += blng[k] * w;
        bs += blnb[k] * w;
    }
    colsum[n] = cs;
    bb1p[n] = bb1[n] + bs;
}

// ---- K1: fused aggregate_start + context MLP + log_z -> out[:,0] ------------
__global__ __launch_bounds__(128) void k_graph(
    const float* __restrict__ node_tokens, const float* __restrict__ question,
    const int* __restrict__ locals_, const int* __restrict__ ptr,
    const float* __restrict__ cw1, const float* __restrict__ cb1,
    const float* __restrict__ cw2, const float* __restrict__ cb2,
    const float* __restrict__ ln1g, const float* __restrict__ ln1b,
    const float* __restrict__ zw1, const float* __restrict__ zb1,
    const float* __restrict__ zw2, const float* __restrict__ zb2,
    float* __restrict__ out)
{
    int g = blockIdx.x, t = threadIdx.x;
    __shared__ float xin[2 * H];
    __shared__ float buf[H];
    __shared__ float r1[2], r2[2];
    __shared__ float sc[16];
    // --- aggregate_start ---
    int p0 = ptr[g], p1 = ptr[g + 1];
    int cnt = p1 - p0; if (cnt > 16) cnt = 16;
    float q = question[(size_t)g * H + t];
    xin[H + t] = q;
    for (int s = 0; s < cnt; ++s) {
        int node = locals_[p0 + s];
        float v = node_tokens[(size_t)node * H + t] * q;
        for (int off = 32; off; off >>= 1) v += __shfl_down(v, off);
        if ((t & 63) == 0) r1[t >> 6] = v;
        __syncthreads();
        if (t == 0) sc[s] = (r1[0] + r1[1]) * 0.08838834764831845f;
        __syncthreads();
    }
    float m = -1e30f;
    for (int s = 0; s < cnt; ++s) m = fmaxf(m, sc[s]);
    float den = 0.f;
    for (int s = 0; s < cnt; ++s) den += expf(sc[s] - m);
    float acc0 = 0.f;
    for (int s = 0; s < cnt; ++s) {
        float a = expf(sc[s] - m) / den;
        acc0 += a * node_tokens[(size_t)locals_[p0 + s] * H + t];
    }
    xin[t] = acc0;
    __syncthreads();
    // --- ctx MLP ---
    float a1 = cb1[t];
    for (int k = 0; k < 2 * H; ++k) a1 += xin[k] * cw1[k * H + t];
    buf[t] = gelu_exact(a1);
    __syncthreads();
    float ctx = cb2[t];
    for (int k = 0; k < H; ++k) ctx += buf[k] * cw2[k * H + t];
    // --- LN + z head ---
    float s1 = ctx, s2 = ctx * ctx;
    for (int off = 32; off; off >>= 1) { s1 += __shfl_down(s1, off); s2 += __shfl_down(s2, off); }
    if ((t & 63) == 0) { r1[t >> 6] = s1; r2[t >> 6] = s2; }
    __syncthreads();
    float mean = (r1[0] + r1[1]) * (1.f / H);
    float var  = (r2[0] + r2[1]) * (1.f / H) - mean * mean;
    float xn = (ctx - mean) * rsqrtf(var + EPS_LN) * ln1g[t] + ln1b[t];
    __syncthreads();
    buf[t] = xn;
    __syncthreads();
    float a2 = zb1[t];
    for (int k = 0; k < H; ++k) a2 += buf[k] * zw1[k * H + t];
    float p = gelu_exact(a2) * zw2[t];
    for (int off = 32; off; off >>= 1) p += __shfl_down(p, off);
    if ((t & 63) == 0) r1[t >> 6] = p;
    __syncthreads();
    if (t == 0) out[(size_t)g * 3 + 0] = r1[0] + r1[1] + zb2[0];
}

// ---- K4: persistent edge MLP via MFMA, full B matrix resident in LDS --------
// 256 blocks x 1024 threads (16 waves). Stage all 96 KB of bf16 weights into
// LDS ONCE per block (one barrier total), then grid-stride over 256-edge
// tiles; each wave owns 16 edges per tile and runs with NO barriers, so 16
// independent waves/CU hide the gather + L2 latency that previously
// serialized behind 24 barriers per 64 edges.
__global__ __launch_bounds__(1024, 4) void k_edges(
    const float* __restrict__ node_tokens, const float* __restrict__ question,
    const float* __restrict__ edge_tokens, const int* __restrict__ edge_batch,
    const int* __restrict__ edge_index,
    const unsigned short* __restrict__ bwbf, const float* __restrict__ colsum,
    const float* __restrict__ bb1p, const float* __restrict__ bw2,
    const float* __restrict__ bb2, float* __restrict__ logits,
    float* __restrict__ sumexp)
{
    __shared__ unsigned short bwlds[49152];   // 96 KB: full 384x128 bf16 W1'
    int t = threadIdx.x, lane = t & 63, w = t >> 6;
    int quad = lane >> 4, n16 = lane & 15;

    // one-time stage of the whole weight matrix: 6144 uint4 = 96 KB
    {
        const uint4* src = (const uint4*)bwbf;
        uint4* dst = (uint4*)bwlds;
        #pragma unroll
        for (int i = 0; i < 6; ++i) dst[t + i * 1024] = src[t + i * 1024];
    }
    // hoist per-(t8,n16) epilogue constants out of the tile loop
    float csv[8], bbv[8], w2v[8];
    #pragma unroll
    for (int t8 = 0; t8 < 8; ++t8) {
        int n = t8 * 16 + n16;
        csv[t8] = colsum[n]; bbv[t8] = bb1p[n]; w2v[t8] = bw2[n];
    }
    float bb2v = bb2[0];
    const int* tgt_idx = edge_index + NEDGES;
    __syncthreads();   // the ONLY barrier

    const int NTILES = (NEDGES + 255) / 256;
    for (int tile = blockIdx.x; tile < NTILES; tile += gridDim.x) {
        int e0w = tile * 256 + w * 16;
        int e = e0w + n16;
        int ec = e < NEDGES ? e : NEDGES - 1;
        int qrow = edge_batch[ec];
        int trow = tgt_idx[ec];
        const float4* ep  = (const float4*)(edge_tokens + (size_t)ec * H);
        const float4* qp  = (const float4*)(question + (size_t)qrow * H);
        const float4* np_ = (const float4*)(node_tokens + (size_t)trow * H);

        float s1 = 0.f, s2 = 0.f;
        short8 frag[12];
        #pragma unroll
        for (int s = 0; s < 12; ++s) {
            int c0 = s * 8 + quad * 2;          // float4 index 0..95 of the 3H row
            const float4* base = (s < 4) ? ep : (s < 8) ? qp : np_;
            int cc = c0 - ((s < 4) ? 0 : (s < 8) ? 32 : 64);
            float4 v0 = base[cc], v1 = base[cc + 1];
            s1 += v0.x + v0.y + v0.z + v0.w + v1.x + v1.y + v1.z + v1.w;
            s2 += v0.x*v0.x + v0.y*v0.y + v0.z*v0.z + v0.w*v0.w
                + v1.x*v1.x + v1.y*v1.y + v1.z*v1.z + v1.w*v1.w;
            short8 f;
            f[0] = (short)f2bf(v0.x); f[1] = (short)f2bf(v0.y);
            f[2] = (short)f2bf(v0.z); f[3] = (short)f2bf(v0.w);
            f[4] = (short)f2bf(v1.x); f[5] = (short)f2bf(v1.y);
            f[6] = (short)f2bf(v1.z); f[7] = (short)f2bf(v1.w);
            frag[s] = f;
        }
        // full-row LN stats: reduce across the 4 quads sharing this edge row
        s1 += __shfl_xor(s1, 16); s1 += __shfl_xor(s1, 32);
        s2 += __shfl_xor(s2, 16); s2 += __shfl_xor(s2, 32);
        float mu  = s1 * (1.f / 384.f);
        float inv = rsqrtf(s2 * (1.f / 384.f) - mu * mu + EPS_LN);

        f32x4 acc[8];
        #pragma unroll
        for (int q = 0; q < 8; ++q) acc[q] = (f32x4){0.f, 0.f, 0.f, 0.f};

        #pragma unroll
        for (int s = 0; s < 12; ++s) {
            #pragma unroll
            for (int t8 = 0; t8 < 8; ++t8) {
                short8 b = *(const short8*)&bwlds[((s * 8 + t8) * 64 + lane) * 8];
                acc[t8] = __builtin_amdgcn_mfma_f32_16x16x32_bf16(frag[s], b, acc[t8], 0, 0, 0);
            }
        }

        // epilogue: y = (acc - mu*colsum)*inv + bb1p ; logit = sum gelu(y)*bw2 + bb2
        #pragma unroll
        for (int r = 0; r < 4; ++r) {
            float mu_r  = __shfl(mu,  quad * 4 + r);
            float inv_r = __shfl(inv, quad * 4 + r);
            float ssum = 0.f;
            #pragma unroll
            for (int t8 = 0; t8 < 8; ++t8) {
                float y = (acc[t8][r] - mu_r * csv[t8]) * inv_r + bbv[t8];
                ssum += gelu_exact(y) * w2v[t8];
            }
            ssum += __shfl_xor(ssum, 1);
            ssum += __shfl_xor(ssum, 2);
            ssum += __shfl_xor(ssum, 4);
            ssum += __shfl_xor(ssum, 8);
            if (n16 == 0) {
                int ei = e0w + quad * 4 + r;
                if (ei < NEDGES) {
                    float lg = ssum + bb2v;
                    logits[ei] = lg;
                    // logits are O(1): exp-sum without max-shift is safe
                    atomicAdd(&sumexp[tgt_idx[ei]], expf(lg));
                }
            }
        }
    }
}

// ---- K6: masked per-graph sum of log-probs (LDS slot aggregation) -----------
__global__ __launch_bounds__(256) void k_logpb(
    const float* __restrict__ logits,
    const int* __restrict__ edge_index,
    const int* __restrict__ edge_batch,
    const void* __restrict__ mask,
    const int* __restrict__ flag,
    const float* __restrict__ sumexp,
    float* __restrict__ logpb, int* __restrict__ selcnt)
{
    __shared__ float lacc[8];
    __shared__ int lcnt[8];
    __shared__ int g0s, big;
    int t = threadIdx.x;
    int e0 = blockIdx.x * 256;
    if (t == 0) {
        int ga = edge_batch[e0 < NEDGES ? e0 : NEDGES - 1];
        int el = e0 + 255; if (el >= NEDGES) el = NEDGES - 1;
        int gb = edge_batch[el];
        g0s = ga; big = (gb - ga > 7);
    }
    if (t < 8) { lacc[t] = 0.f; lcnt[t] = 0; }
    __syncthreads();
    int e = e0 + t;
    if (e < NEDGES) {
        int mode = *flag;
        bool sel;
        if (mode & 2)      sel = ((const float*)mask)[e] != 0.f;
        else if (mode & 1) sel = ((const unsigned char*)mask)[e] != 0;
        else               sel = ((const int*)mask)[e] != 0;
        if (sel) {
            int tg = edge_index[NEDGES + e];
            float lp = logits[e] - logf(sumexp[tg]);
            int g = edge_batch[e];
            if (!big) {
                atomicAdd(&lacc[g - g0s], lp);
                atomicAdd(&lcnt[g - g0s], 1);
            } else {
                atomicAdd(&logpb[g], lp);
                atomicAdd(&selcnt[g], 1);
            }
        }
    }
    __syncthreads();
    if (t < 8 && !big && lcnt[t] > 0) {
        atomicAdd(&logpb[g0s + t], lacc[t]);
        atomicAdd(&selcnt[g0s + t], lcnt[t]);
    }
}

// ---- K7: finalize out[:,1] and out[:,2] -------------------------------------
__global__ __launch_bounds__(1024) void k_final(const float* __restrict__ logpb,
                                                const int* __restrict__ selcnt,
                                                float* __restrict__ out)
{
    int g = threadIdx.x;
    float lpb = logpb[g];
    int has = selcnt[g] > 0;
    float s = has ? -lpb : 0.f;
    int c = has;
    __shared__ float rn[16];
    __shared__ int rh[16];
    __shared__ float pbnll_s;
    for (int off = 32; off; off >>= 1) { s += __shfl_down(s, off); c += __shfl_down(c, off); }
    if ((g & 63) == 0) { rn[g >> 6] = s; rh[g >> 6] = c; }
    __syncthreads();
    if (g == 0) {
        float ts = 0.f; int tc = 0;
        for (int i = 0; i < 16; ++i) { ts += rn[i]; tc += rh[i]; }
        pbnll_s = ts / (float)(tc > 0 ? tc : 1);
    }
    __syncthreads();
    out[(size_t)g * 3 + 1] = lpb;
    out[(size_t)g * 3 + 2] = pbnll_s;
}

extern "C" void kernel_launch(void* const* d_in, const int* in_sizes, int n_in,
                              void* d_out, int out_size, void* d_ws, size_t ws_size,
                              hipStream_t stream) {
    const float* node_tokens = (const float*)d_in[0];
    const float* question    = (const float*)d_in[1];
    const float* edge_tokens = (const float*)d_in[2];
    const int*   locals_     = (const int*)d_in[3];
    const int*   ptr         = (const int*)d_in[4];
    const int*   edge_batch  = (const int*)d_in[5];
    const void*  mask        = d_in[6];
    const int*   edge_index  = (const int*)d_in[7];
    const float* ln1g = (const float*)d_in[8];
    const float* ln1b = (const float*)d_in[9];
    const float* zw1  = (const float*)d_in[10];
    const float* zb1  = (const float*)d_in[11];
    const float* zw2  = (const float*)d_in[12];
    const float* zb2  = (const float*)d_in[13];
    const float* cw1  = (const float*)d_in[14];
    const float* cb1  = (const float*)d_in[15];
    const float* cw2  = (const float*)d_in[16];
    const float* cb2  = (const float*)d_in[17];
    const float* blng = (const float*)d_in[18];
    const float* blnb = (const float*)d_in[19];
    const float* bw1  = (const float*)d_in[20];
    const float* bb1  = (const float*)d_in[21];
    const float* bw2  = (const float*)d_in[22];
    const float* bb2  = (const float*)d_in[23];
    float* out = (float*)d_out;

    // workspace layout (float units)
    float* ws = (float*)d_ws;
    float* sumexp  = ws;                                // 100000 (zeroed)
    float* logpb   = ws + 100000;                       // 1024  (zeroed)
    int*   selcnt  = (int*)(ws + 101024);               // 1024  (zeroed)
    int*   flag    = (int*)(ws + 102048);               // 1     (zeroed)
    float* logits  = ws + 102052;                       // 500000
    float* colsum  = ws + 602052;                       // 128
    float* bb1p    = ws + 602180;                       // 128
    unsigned short* bwbf = (unsigned short*)(ws + 602308); // 49152 bf16 (16B-aligned)

    hipMemsetAsync(d_ws, 0, (size_t)102049 * 4, stream);
    k_probe_mask<<<1, 256, 0, stream>>>((const unsigned*)mask, flag);
    k_prep<<<192, 256, 0, stream>>>(bw1, blng, bwbf);
    k_prep2<<<1, 128, 0, stream>>>(bw1, blng, blnb, bb1, colsum, bb1p);
    k_graph<<<G_NUM, 128, 0, stream>>>(node_tokens, question, locals_, ptr,
                                       cw1, cb1, cw2, cb2, ln1g, ln1b,
                                       zw1, zb1, zw2, zb2, out);
    k_edges<<<256, 1024, 0, stream>>>(node_tokens, question, edge_tokens,
                                      edge_batch, edge_index, bwbf,
                                      colsum, bb1p, bw2, bb2,
                                      logits, sumexp);
    int eb = (NEDGES + 255) / 256;
    k_logpb<<<eb, 256, 0, stream>>>(logits, edge_index, edge_batch, mask, flag,
                                    sumexp, logpb, selcnt);
    k_final<<<1, 1024, 0, stream>>>(logpb, selcnt, out);
}